// Round 3
// baseline (1040.263 us; speedup 1.0000x reference)
//
#include <hip/hip_runtime.h>

#define NN 200000
#define EE 6400000L
#define NBUCK 1563          // ceil(200000/128)
#define NB8 (NBUCK * 8)     // 12504 (bucket,group) sub-regions

// ---------------------------------------------------------------------------
// Edge-index dtype hedge (int64 vs int32): if int64 with values < 2^31, every
// odd 32-bit word is zero. flag=1 -> int64 (word idx = elem<<1), 0 -> int32.
// ---------------------------------------------------------------------------
__global__ void k_detect(const int* __restrict__ w, int* __restrict__ flag) {
    __shared__ int any;
    if (threadIdx.x == 0) any = 0;
    __syncthreads();
    int found = 0;
    for (int i = threadIdx.x; i < 8192; i += 256)
        if (w[2 * i + 1] != 0) found = 1;
    if (found) atomicOr(&any, 1);
    __syncthreads();
    if (threadIdx.x == 0) flag[0] = any ? 0 : 1;
}

// Histogram of (dst-bucket, block-group): counts[(d>>7)*8 + (blockIdx&7)]++
__global__ void k_hist(const int* __restrict__ ew, const int* __restrict__ flag,
                       int* __restrict__ counts, long e) {
    long i = (long)blockIdx.x * 256 + threadIdx.x;
    if (i >= e) return;
    int shift = *flag;
    int d = ew[(EE + i) << shift];
    atomicAdd(&counts[(d >> 7) * 8 + (blockIdx.x & 7)], 1);
}

// Single-block exclusive scan of counts[NB8] -> offs, curs; offs[NB8] = total.
__global__ __launch_bounds__(1024) void k_bscan(
    const int* __restrict__ counts, int* __restrict__ offs,
    int* __restrict__ curs, int nb8) {
    __shared__ int ws[16];
    __shared__ int carry;
    int t = threadIdx.x;
    if (t == 0) carry = 0;
    __syncthreads();
    for (int base = 0; base < nb8; base += 1024) {
        int i = base + t;
        int v = (i < nb8) ? counts[i] : 0;
        int lane = t & 63, w = t >> 6;
        int s = v;
#pragma unroll
        for (int o = 1; o < 64; o <<= 1) {
            int u = __shfl_up(s, o, 64);
            if (lane >= o) s += u;
        }
        if (lane == 63) ws[w] = s;
        __syncthreads();
        int add = carry;
        for (int k = 0; k < w; ++k) add += ws[k];
        if (i < nb8) {
            int excl = s - v + add;
            offs[i] = excl;
            curs[i] = excl;
        }
        __syncthreads();
        if (t == 0) {
            int tot = 0;
            for (int k = 0; k < 16; ++k) tot += ws[k];
            carry += tot;
        }
        __syncthreads();
    }
    if (t == 0) offs[nb8] = carry;
}

// Partition: append packed {src[17:0], local_dst[24:18]} into (bucket,group).
__global__ void k_part(const int* __restrict__ ew, const int* __restrict__ flag,
                       int* __restrict__ curs, unsigned* __restrict__ stage, long e) {
    long i = (long)blockIdx.x * 256 + threadIdx.x;
    if (i >= e) return;
    int shift = *flag;
    int s = ew[i << shift];
    int d = ew[(EE + i) << shift];
    int pos = atomicAdd(&curs[(d >> 7) * 8 + (blockIdx.x & 7)], 1);
    stage[pos] = (unsigned)s | ((unsigned)(d & 127) << 18);
}

// Per-bucket: count local degrees, scan, emit node arrays, place src into CSR.
__global__ __launch_bounds__(256) void k_bucket(
    const unsigned* __restrict__ stage, const int* __restrict__ offs,
    float* __restrict__ dis, int* __restrict__ offn, int* __restrict__ degn,
    unsigned* __restrict__ csr, int n) {
    int B = blockIdx.x;
    int t = threadIdx.x;
    __shared__ int cnt[128];
    __shared__ int cur[128];
    __shared__ int wtot;
    int bstart = offs[B * 8];
    int bend = offs[B * 8 + 8];
    if (t < 128) cnt[t] = 0;
    __syncthreads();
    for (int i = bstart + t; i < bend; i += 256)
        atomicAdd(&cnt[stage[i] >> 18], 1);
    __syncthreads();
    int s = 0, c = 0;
    if (t < 128) {
        c = cnt[t];
        s = c;
        int lane = t & 63;
#pragma unroll
        for (int o = 1; o < 64; o <<= 1) {
            int u = __shfl_up(s, o, 64);
            if (lane >= o) s += u;
        }
        if (t == 63) wtot = s;
    }
    __syncthreads();
    if (t < 128) {
        int excl = s - c + ((t >= 64) ? wtot : 0);
        cur[t] = excl;
        int node = B * 128 + t;
        if (node < n) {
            offn[node] = bstart + excl;
            degn[node] = c;
            dis[node] = rsqrtf((float)(c + 1));
        }
    }
    __syncthreads();
    for (int i = bstart + t; i < bend; i += 256) {
        unsigned w = stage[i];
        int pos = bstart + atomicAdd(&cur[w >> 18], 1);
        csr[pos] = w & 0x3FFFF;
    }
}

// Layer 1 matmul: hw = x @ W1  (x:[N,256], W1:[256,16])
__global__ __launch_bounds__(256) void k_mm1(
    const float* __restrict__ x, const float* __restrict__ W,
    float* __restrict__ hw, int n) {
    __shared__ float Wl[256 * 16];
    int t = threadIdx.x;
#pragma unroll
    for (int i = 0; i < 4; ++i)
        ((float4*)Wl)[t + i * 256] = ((const float4*)W)[t + i * 256];
    __syncthreads();

    int node = blockIdx.x * 256 + t;
    if (node >= n) return;

    const float4* xr = (const float4*)(x + (long)node * 256);
    float acc[16];
#pragma unroll
    for (int o = 0; o < 16; ++o) acc[o] = 0.f;

#pragma unroll 8
    for (int kk = 0; kk < 64; ++kk) {
        float4 xv = xr[kk];
#pragma unroll
        for (int q = 0; q < 4; ++q) {
            float xs = (q == 0) ? xv.x : (q == 1) ? xv.y : (q == 2) ? xv.z : xv.w;
            const float4* wr = (const float4*)&Wl[(kk * 4 + q) * 16];
#pragma unroll
            for (int oo = 0; oo < 4; ++oo) {
                float4 wv = wr[oo];
                acc[oo * 4 + 0] = fmaf(xs, wv.x, acc[oo * 4 + 0]);
                acc[oo * 4 + 1] = fmaf(xs, wv.y, acc[oo * 4 + 1]);
                acc[oo * 4 + 2] = fmaf(xs, wv.z, acc[oo * 4 + 2]);
                acc[oo * 4 + 3] = fmaf(xs, wv.w, acc[oo * 4 + 3]);
            }
        }
    }
    float4* hwo = (float4*)(hw + (long)node * 16);
#pragma unroll
    for (int oo = 0; oo < 4; ++oo)
        hwo[oo] = make_float4(acc[oo * 4], acc[oo * 4 + 1], acc[oo * 4 + 2], acc[oo * 4 + 3]);
}

// 16x16 matmul: hw = h @ W (h already relu'd by the gather epilogue)
__global__ __launch_bounds__(256) void k_mm2(
    const float* __restrict__ h, const float* __restrict__ W,
    float* __restrict__ hw, int n) {
    __shared__ float Wl[256];
    if (threadIdx.x < 64) ((float4*)Wl)[threadIdx.x] = ((const float4*)W)[threadIdx.x];
    __syncthreads();
    int node = blockIdx.x * 256 + threadIdx.x;
    if (node >= n) return;
    float hv[16];
    const float4* hr = (const float4*)(h + (long)node * 16);
#pragma unroll
    for (int i = 0; i < 4; ++i) {
        float4 v = hr[i];
        hv[i * 4 + 0] = v.x; hv[i * 4 + 1] = v.y; hv[i * 4 + 2] = v.z; hv[i * 4 + 3] = v.w;
    }
    float acc[16];
#pragma unroll
    for (int o = 0; o < 16; ++o) acc[o] = 0.f;
#pragma unroll
    for (int k = 0; k < 16; ++k) {
        float xs = hv[k];
#pragma unroll
        for (int o = 0; o < 16; ++o) acc[o] = fmaf(xs, Wl[k * 16 + o], acc[o]);
    }
    float4* hwo = (float4*)(hw + (long)node * 16);
#pragma unroll
    for (int oo = 0; oo < 4; ++oo)
        hwo[oo] = make_float4(acc[oo * 4], acc[oo * 4 + 1], acc[oo * 4 + 2], acc[oo * 4 + 3]);
}

// 16x1 matmul: hw3 = h @ W3 (h already relu'd)
__global__ __launch_bounds__(256) void k_mm3(
    const float* __restrict__ h, const float* __restrict__ W,
    float* __restrict__ hw3, int n) {
    int node = blockIdx.x * 256 + threadIdx.x;
    if (node >= n) return;
    const float4* hr = (const float4*)(h + (long)node * 16);
    float acc = 0.f;
#pragma unroll
    for (int i = 0; i < 4; ++i) {
        float4 v = hr[i];
        acc = fmaf(v.x, W[i * 4 + 0], acc);
        acc = fmaf(v.y, W[i * 4 + 1], acc);
        acc = fmaf(v.z, W[i * 4 + 2], acc);
        acc = fmaf(v.w, W[i * 4 + 3], acc);
    }
    hw3[node] = acc;
}

// Gather-aggregate, 16 channels. Block = 16 nodes x 16 lanes(=channels).
// agg[i,ch] = relu?( b[ch] + dv*( sum_e dis[s]*hw[s,ch] + dv*hw[i,ch] ) )
template <int RELU>
__global__ __launch_bounds__(256) void k_g16(
    const int* __restrict__ offn, const int* __restrict__ degn,
    const unsigned* __restrict__ csr, const float* __restrict__ dis,
    const float* __restrict__ hw, const float* __restrict__ b,
    float* __restrict__ agg, int n) {
    int t = threadIdx.x;
    int node = blockIdx.x * 16 + (t >> 4);
    int ch = t & 15;
    if (node >= n) return;
    int s0 = offn[node];
    int dg = degn[node];
    float acc0 = 0.f, acc1 = 0.f, acc2 = 0.f, acc3 = 0.f;
    int k = 0;
    for (; k + 3 < dg; k += 4) {
        unsigned e0 = csr[s0 + k], e1 = csr[s0 + k + 1];
        unsigned e2 = csr[s0 + k + 2], e3 = csr[s0 + k + 3];
        acc0 = fmaf(dis[e0], hw[(long)e0 * 16 + ch], acc0);
        acc1 = fmaf(dis[e1], hw[(long)e1 * 16 + ch], acc1);
        acc2 = fmaf(dis[e2], hw[(long)e2 * 16 + ch], acc2);
        acc3 = fmaf(dis[e3], hw[(long)e3 * 16 + ch], acc3);
    }
    for (; k < dg; ++k) {
        unsigned e0 = csr[s0 + k];
        acc0 = fmaf(dis[e0], hw[(long)e0 * 16 + ch], acc0);
    }
    float dv = dis[node];
    float acc = (acc0 + acc1) + (acc2 + acc3);
    float r = fmaf(dv, fmaf(dv, hw[(long)node * 16 + ch], acc), b[ch]);
    if (RELU) r = fmaxf(r, 0.f);
    agg[(long)node * 16 + ch] = r;
}

// Gather-aggregate, 1 channel. Block = 16 nodes x 16 lanes; lanes split edges.
__global__ __launch_bounds__(256) void k_g1(
    const int* __restrict__ offn, const int* __restrict__ degn,
    const unsigned* __restrict__ csr, const float* __restrict__ dis,
    const float* __restrict__ hw3, const float* __restrict__ b,
    float* __restrict__ out, int n) {
    int t = threadIdx.x;
    int node = blockIdx.x * 16 + (t >> 4);
    int ln = t & 15;
    if (node >= n) return;
    int s0 = offn[node], dg = degn[node];
    float acc = 0.f;
    for (int k = ln; k < dg; k += 16) {
        unsigned e = csr[s0 + k];
        acc = fmaf(dis[e], hw3[e], acc);
    }
#pragma unroll
    for (int o = 8; o >= 1; o >>= 1) acc += __shfl_down(acc, o, 16);
    if (ln == 0) {
        float dv = dis[node];
        out[node] = fmaf(dv, fmaf(dv, hw3[node], acc), b[0]);
    }
}

extern "C" void kernel_launch(void* const* d_in, const int* in_sizes, int n_in,
                              void* d_out, int out_size, void* d_ws, size_t ws_size,
                              hipStream_t stream) {
    const float* x  = (const float*)d_in[0];
    const int*   ew = (const int*)d_in[1];
    const float* W1 = (const float*)d_in[2];
    const float* b1 = (const float*)d_in[3];
    const float* W2 = (const float*)d_in[4];
    const float* b2 = (const float*)d_in[5];
    const float* W3 = (const float*)d_in[6];
    const float* b3 = (const float*)d_in[7];
    float* out = (float*)d_out;

    // Workspace layout (4-byte words), ~80 MB total
    unsigned* stage  = (unsigned*)d_ws;            // 6,400,000
    unsigned* csr    = stage + EE;                 // 6,400,000
    int*      counts = (int*)(csr + EE);           // 12,512
    int*      offs   = counts + 12512;             // 12,512 (+1 total slot inside)
    int*      curs   = offs + 12512;               // 12,512
    int*      offn   = curs + 12512;               // 200,064
    int*      degn   = offn + 200064;              // 200,064
    float*    dis    = (float*)(degn + 200064);    // 200,064
    int*      flag   = (int*)(dis + 200064);       // 16
    float*    bufA   = (float*)(flag + 16);        // 3,276,800 (hw / hw3)
    float*    bufB   = bufA + 3276800;             // 3,276,800 (agg / h)

    const int n = NN;
    const long e = EE;
    int nb = (n + 255) / 256;         // 782
    int eb = (int)((e + 255) / 256);  // 25000
    int gb = (n + 15) / 16;           // 12500

    k_detect<<<1, 256, 0, stream>>>(ew, flag);
    hipMemsetAsync(counts, 0, 12512 * sizeof(int), stream);

    // CSR build: histogram -> scan -> partition -> per-bucket counting sort
    k_hist<<<eb, 256, 0, stream>>>(ew, flag, counts, e);
    k_bscan<<<1, 1024, 0, stream>>>(counts, offs, curs, NB8);
    k_part<<<eb, 256, 0, stream>>>(ew, flag, curs, stage, e);
    k_bucket<<<NBUCK, 256, 0, stream>>>(stage, offs, dis, offn, degn, csr, n);

    // Layer 1
    k_mm1<<<nb, 256, 0, stream>>>(x, W1, bufA, n);
    k_g16<1><<<gb, 256, 0, stream>>>(offn, degn, csr, dis, bufA, b1, bufB, n);
    // Layer 2
    k_mm2<<<nb, 256, 0, stream>>>(bufB, W2, bufA, n);
    k_g16<1><<<gb, 256, 0, stream>>>(offn, degn, csr, dis, bufA, b2, bufB, n);
    // Layer 3
    k_mm3<<<nb, 256, 0, stream>>>(bufB, W3, bufA, n);
    k_g1<<<gb, 256, 0, stream>>>(offn, degn, csr, dis, bufA, b3, out, n);
}